// Round 5
// baseline (582.733 us; speedup 1.0000x reference)
//
#include <hip/hip_runtime.h>
#include <math.h>

// Problem constants (B=4, L=4096, n=4, C=1024) — all tensors fp32
#define DTOT   4096          // n*C
#define NTOK   16384         // B*L
#define NJ     24            // 4 pre + 4 post + 16 res dot products
#define NG     25            // NJ dots + sumsq
#define DC     256           // d-elements per chunk in dots kernel
#define NCHUNK (DTOT / DC)   // 16
#define TPW    32            // tokens per wave (8 lanes-sub x 4 per-thread)
#define TPBK   128           // tokens per dots-block (4 waves)

typedef float floatx4 __attribute__((ext_vector_type(4)));  // native vec for nontemporal builtin

// ---------------------------------------------------------------------------
// Kernel 0: Wtj[j][d] = W[j][d] * norm_w[d]  (j-major, same layout as inputs)
// ---------------------------------------------------------------------------
__global__ void prep_kernel(const float* __restrict__ Wpre,
                            const float* __restrict__ Wpost,
                            const float* __restrict__ Wres,
                            const float* __restrict__ nw,
                            float* __restrict__ Wtj) {
    int i = blockIdx.x * 256 + threadIdx.x;   // over 24*4096
    if (i >= NJ * DTOT) return;
    int j = i / DTOT;
    int d = i - j * DTOT;
    float w;
    if (j < 4)       w = Wpre [i];
    else if (j < 8)  w = Wpost[i - 4 * DTOT];
    else             w = Wres [i - 8 * DTOT];
    Wtj[i] = w * nw[d];
}

// ---------------------------------------------------------------------------
// Kernel 1: partial dots + sumsq per (token, d-chunk).
// Round-3 was LDS-issue-bound: 192 per-lane ds_read_b128 per wave served ONE
// token set -> ~123us of LDS reads vs 43us HBM floor. Now each thread carries
// FOUR tokens (k=0..3), so each weight ds_read_b128 feeds 4 accumulator sets:
// LDS cost /4 ~= 31us < HBM floor -> memory-bound.
// Lane map: lane = t8*8+dp. x-load instr = 8 tokens x one aligned 128B line
// (dense, zero over-fetch — kept from round 3). Weight read wl4[j*64+i*8+dp]:
// 8 distinct 16B rows covering all 32 banks once, 8-way same-addr broadcast
// (free) -> conflict-free.
// Grid: x = chunk (fast), y = token-group (slow) so the LAST tokens' complete
// rows are what remains L3-resident for out_kernel's reversed walk.
// ---------------------------------------------------------------------------
__global__ __launch_bounds__(256, 3) void dots_kernel(
        const float* __restrict__ x,
        const float* __restrict__ Wtj,
        float* __restrict__ Gpart) {
    __shared__ float wlds[NJ * DC];   // 24*256*4 = 24576 B

    const int tid = threadIdx.x;
    const int ch  = blockIdx.x;       // d chunk (0..15)  — fast axis
    const int tg  = blockIdx.y;       // token group (0..127) — slow axis

    // Stage weights: 24 rows x 256 floats = 1536 float4
    {
        const float4* src = (const float4*)Wtj;   // [j][DTOT/4]
        float4* dst = (float4*)wlds;
        #pragma unroll
        for (int r = 0; r < 6; ++r) {
            int idx = r * 256 + tid;              // 0..1535
            int j = idx >> 6;
            int f = idx & 63;
            dst[idx] = src[(size_t)j * (DTOT / 4) + ch * (DC / 4) + f];
        }
    }
    __syncthreads();

    const int w    = tid >> 6;        // wave 0..3
    const int lane = tid & 63;
    const int t8   = lane >> 3;       // 0..7 token-sub
    const int dp   = lane & 7;        // 0..7 d-slot
    const int tok0 = tg * TPBK + w * TPW + t8;   // thread's tokens: +8k

    const float4* __restrict__ xp0 =
        (const float4*)(x + (size_t)(tok0     ) * DTOT + ch * DC);
    const float4* __restrict__ xp1 =
        (const float4*)(x + (size_t)(tok0 +  8) * DTOT + ch * DC);
    const float4* __restrict__ xp2 =
        (const float4*)(x + (size_t)(tok0 + 16) * DTOT + ch * DC);
    const float4* __restrict__ xp3 =
        (const float4*)(x + (size_t)(tok0 + 24) * DTOT + ch * DC);
    const float4* __restrict__ wl4 = (const float4*)wlds;   // [j][64]

    float a0[NG], a1[NG], a2[NG], a3[NG];
    #pragma unroll
    for (int j = 0; j < NG; ++j) { a0[j] = 0.f; a1[j] = 0.f; a2[j] = 0.f; a3[j] = 0.f; }

    float4 x0 = xp0[dp], x1 = xp1[dp], x2 = xp2[dp], x3 = xp3[dp];

    #pragma unroll
    for (int i = 0; i < 8; ++i) {
        float4 n0 = x0, n1 = x1, n2 = x2, n3 = x3;
        if (i < 7) {
            const int nb = (i + 1) * 8 + dp;
            n0 = xp0[nb]; n1 = xp1[nb]; n2 = xp2[nb]; n3 = xp3[nb];
        }
        const int base = i * 8 + dp;
        #pragma unroll
        for (int j = 0; j < NJ; ++j) {
            const float4 w4 = wl4[j * 64 + base];
            a0[j] += x0.x * w4.x + x0.y * w4.y + x0.z * w4.z + x0.w * w4.w;
            a1[j] += x1.x * w4.x + x1.y * w4.y + x1.z * w4.z + x1.w * w4.w;
            a2[j] += x2.x * w4.x + x2.y * w4.y + x2.z * w4.z + x2.w * w4.w;
            a3[j] += x3.x * w4.x + x3.y * w4.y + x3.z * w4.z + x3.w * w4.w;
        }
        a0[NG-1] += x0.x*x0.x + x0.y*x0.y + x0.z*x0.z + x0.w*x0.w;
        a1[NG-1] += x1.x*x1.x + x1.y*x1.y + x1.z*x1.z + x1.w*x1.w;
        a2[NG-1] += x2.x*x2.x + x2.y*x2.y + x2.z*x2.z + x2.w*x2.w;
        a3[NG-1] += x3.x*x3.x + x3.y*x3.y + x3.z*x3.z + x3.w*x3.w;
        x0 = n0; x1 = n1; x2 = n2; x3 = n3;
    }

    // reduce over dp (lane bits 0..2) -> per-token totals
    #pragma unroll
    for (int j = 0; j < NG; ++j) {
        float v0 = a0[j], v1 = a1[j], v2 = a2[j], v3 = a3[j];
        v0 += __shfl_xor(v0, 1, 64); v1 += __shfl_xor(v1, 1, 64);
        v2 += __shfl_xor(v2, 1, 64); v3 += __shfl_xor(v3, 1, 64);
        v0 += __shfl_xor(v0, 2, 64); v1 += __shfl_xor(v1, 2, 64);
        v2 += __shfl_xor(v2, 2, 64); v3 += __shfl_xor(v3, 2, 64);
        v0 += __shfl_xor(v0, 4, 64); v1 += __shfl_xor(v1, 4, 64);
        v2 += __shfl_xor(v2, 4, 64); v3 += __shfl_xor(v3, 4, 64);
        a0[j] = v0; a1[j] = v1; a2[j] = v2; a3[j] = v3;
    }

    if (dp == 0) {
        float* gp = Gpart + (size_t)ch * NG * NTOK + tok0;
        #pragma unroll
        for (int j = 0; j < NG; ++j) {
            gp[(size_t)j * NTOK     ] = a0[j];
            gp[(size_t)j * NTOK +  8] = a1[j];
            gp[(size_t)j * NTOK + 16] = a2[j];
            gp[(size_t)j * NTOK + 24] = a3[j];
        }
    }
}

// ---------------------------------------------------------------------------
// Kernel 2: wave-per-token, barrier-free. 1024-thread blocks = 16 consecutive
// tokens; token order REVERSED so first x re-reads hit the tail of x that
// dots_kernel left in the 256MB L3 (dots' slow axis = token groups, so the
// tail is complete rows of the last tokens). Output stores are NONTEMPORAL
// so the 268MB of writes don't evict x from L3.
// ---------------------------------------------------------------------------
__global__ __launch_bounds__(1024) void out_kernel(
        const float* __restrict__ x,
        const float* __restrict__ Gpart,
        const float* __restrict__ bpre,
        const float* __restrict__ bpost,
        const float* __restrict__ bres,
        const float* __restrict__ apre,
        const float* __restrict__ apost,
        const float* __restrict__ ares,
        float* __restrict__ out) {
    const int lane  = threadIdx.x & 63;
    const int token = (NTOK - 16 - blockIdx.x * 16) + (threadIdx.x >> 6);

    // Phase 1: per-gate chunk reduction (lanes 0..24 active, 16 indep loads)
    float s = 0.f;
    if (lane < NG) {
        const float* gp = Gpart + (size_t)lane * NTOK + token;
        #pragma unroll
        for (int c = 0; c < NCHUNK; ++c)
            s += gp[(size_t)c * NG * NTOK];
    }

    // All-gather the 25 sums to every lane (wave-wide, no LDS, no barrier)
    float g[NG];
    #pragma unroll
    for (int j = 0; j < NG; ++j) g[j] = __shfl(s, j, 64);

    // Phase 2: gates + Cayley — computed redundantly by all 64 lanes
    const float inv = rsqrtf(g[NG-1] * (1.0f / DTOT) + 1e-6f);
    const float a_pre  = apre[0];
    const float a_post = apost[0];
    const float a_res  = ares[0];

    float hpre[4], hpost[4];
    #pragma unroll
    for (int i = 0; i < 4; ++i) {
        float z1 = a_pre  * g[i]     * inv + bpre[i];
        hpre[i]  = 1.f / (1.f + __expf(-z1));
        float z2 = a_post * g[4 + i] * inv + bpost[i];
        hpost[i] = 2.f / (1.f + __expf(-z2));
    }

    float M[4][4];
    #pragma unroll
    for (int i = 0; i < 4; ++i)
        #pragma unroll
        for (int j = 0; j < 4; ++j)
            M[i][j] = a_res * g[8 + i * 4 + j] * inv + bres[i * 4 + j];

    // Cayley: Q = (I - S)^{-1} (I + S), S = 0.5 (M - M^T)
    float A[4][8];
    #pragma unroll
    for (int i = 0; i < 4; ++i)
        #pragma unroll
        for (int j = 0; j < 4; ++j) {
            float S = 0.5f * (M[i][j] - M[j][i]);
            float I = (i == j) ? 1.f : 0.f;
            A[i][j]     = I - S;
            A[i][4 + j] = I + S;
        }
    // Gauss-Jordan; (I - S) with small skew S is diag-dominant, no pivoting
    #pragma unroll
    for (int k = 0; k < 4; ++k) {
        float pv = 1.f / A[k][k];
        #pragma unroll
        for (int c = 0; c < 8; ++c) A[k][c] *= pv;
        #pragma unroll
        for (int i = 0; i < 4; ++i) {
            if (i == k) continue;
            float f = A[i][k];
            #pragma unroll
            for (int c = 0; c < 8; ++c) A[i][c] -= f * A[k][c];
        }
    }
    // fused coefficients: out[m] = sum_n (Q[m][n] + hpost[m]*hpre[n]) x[n]
    float cf[16];
    #pragma unroll
    for (int m = 0; m < 4; ++m)
        #pragma unroll
        for (int n = 0; n < 4; ++n)
            cf[m * 4 + n] = A[m][4 + n] + hpost[m] * hpre[n];

    // Phase 3: outputs — lane covers 4 float4 positions per n-row (coalesced)
    const float* xt = x + (size_t)token * DTOT;
    float* ot = out + (size_t)token * DTOT;

    #pragma unroll
    for (int cc = 0; cc < 4; ++cc) {
        const int c0 = cc * 256 + lane * 4;
        float4 xv[4];
        #pragma unroll
        for (int n = 0; n < 4; ++n)
            xv[n] = *(const float4*)(xt + n * 1024 + c0);
        #pragma unroll
        for (int m = 0; m < 4; ++m) {
            floatx4 o;
            o.x = cf[m*4+0] * xv[0].x; o.y = cf[m*4+0] * xv[0].y;
            o.z = cf[m*4+0] * xv[0].z; o.w = cf[m*4+0] * xv[0].w;
            #pragma unroll
            for (int n = 1; n < 4; ++n) {
                const float c = cf[m * 4 + n];
                o.x += c * xv[n].x;
                o.y += c * xv[n].y;
                o.z += c * xv[n].z;
                o.w += c * xv[n].w;
            }
            __builtin_nontemporal_store(o, (floatx4*)(ot + m * 1024 + c0));
        }
    }
}

// ---------------------------------------------------------------------------
extern "C" void kernel_launch(void* const* d_in, const int* in_sizes, int n_in,
                              void* d_out, int out_size, void* d_ws, size_t ws_size,
                              hipStream_t stream) {
    const float* x     = (const float*)d_in[0];
    const float* nw    = (const float*)d_in[1];
    const float* Wpre  = (const float*)d_in[2];
    const float* Wpost = (const float*)d_in[3];
    const float* Wres  = (const float*)d_in[4];
    const float* bpre  = (const float*)d_in[5];
    const float* bpost = (const float*)d_in[6];
    const float* bres  = (const float*)d_in[7];
    const float* apre  = (const float*)d_in[8];
    const float* apost = (const float*)d_in[9];
    const float* ares  = (const float*)d_in[10];
    float* out = (float*)d_out;

    // workspace: Wtj (24*4096 fp32 = 384KB) | Gpart (16*25*16384 fp32 ~ 26.2MB)
    float* Wtj   = (float*)d_ws;
    float* Gpart = (float*)((char*)d_ws + (size_t)NJ * DTOT * sizeof(float));

    prep_kernel<<<(NJ * DTOT + 255) / 256, 256, 0, stream>>>(Wpre, Wpost, Wres, nw, Wtj);

    dim3 ga(NCHUNK, NTOK / TPBK);   // (16 fast, 128 slow) = 2048 blocks
    dots_kernel<<<ga, 256, 0, stream>>>(x, Wtj, Gpart);

    out_kernel<<<NTOK / 16, 1024, 0, stream>>>(x, Gpart, bpre, bpost, bres,
                                               apre, apost, ares, out);
}